// Round 1
// baseline (491.031 us; speedup 1.0000x reference)
//
#include <hip/hip_runtime.h>

#define T_FULL 4096
#define D 128
#define K 1024
#define NVEC 65536           // 16*4096
#define BDT 8388608          // 16*128*4096
#define KW 32                // k-tile per wave per iteration

// ---------------- codebook squared norms ----------------
__global__ __launch_bounds__(128) void ee_kernel(const float* __restrict__ cb,
                                                 float* __restrict__ ee) {
  int k = blockIdx.x;
  int d = threadIdx.x;
  float v = cb[(size_t)k * D + d];
  v *= v;
#pragma unroll
  for (int o = 32; o > 0; o >>= 1) v += __shfl_down(v, o, 64);
  __shared__ float tmp[2];
  if ((d & 63) == 0) tmp[d >> 6] = v;
  __syncthreads();
  if (d == 0) ee[k] = tmp[0] + tmp[1];
}

// ---------------- main: distances + argmin + quantize + loss + hist ----------------
__global__ __launch_bounds__(256, 4) void vq_main(
    const float* __restrict__ inp, const float* __restrict__ cb,
    const float* __restrict__ ee, unsigned int* __restrict__ counts,
    float* __restrict__ lparts, float* __restrict__ out_q,
    float* __restrict__ out_idx) {
  __shared__ __align__(16) float Xs[D * 64];   // [d][t], 32 KB
  __shared__ float red_val[256];
  __shared__ int   red_idx[256];
  __shared__ int   idx_sh[64];

  const int tid  = threadIdx.x;
  const int b    = blockIdx.x >> 6;
  const int t0   = (blockIdx.x & 63) << 6;
  const int lane = tid & 63;
  const int wv   = __builtin_amdgcn_readfirstlane(tid >> 6);  // force uniform

  // ---- stage X tile [128 d][64 t], coalesced float4 rows ----
  const float* xin = inp + (size_t)b * D * T_FULL + t0;
#pragma unroll
  for (int i = 0; i < 8; ++i) {
    int idx = tid + i * 256;                 // 0..2047 float4s
    int d = idx >> 4, t4 = (idx & 15) << 2;
    float4 v = *(const float4*)(xin + (size_t)d * T_FULL + t4);
    *(float4*)(&Xs[d * 64 + t4]) = v;
  }
  __syncthreads();

  float bestv = 3.4e38f;
  int   besti = 0;

  // wave wv owns k-tiles {wv*KW + 128*m}; lane owns t = t0+lane
  for (int kt = wv * KW; kt < K; kt += 4 * KW) {
    float acc[KW];
#pragma unroll
    for (int k = 0; k < KW; ++k) acc[k] = 0.f;

    for (int d4 = 0; d4 < D / 4; ++d4) {
      float x0 = Xs[(d4 * 4 + 0) * 64 + lane];
      float x1 = Xs[(d4 * 4 + 1) * 64 + lane];
      float x2 = Xs[(d4 * 4 + 2) * 64 + lane];
      float x3 = Xs[(d4 * 4 + 3) * 64 + lane];
#pragma unroll
      for (int k = 0; k < KW; ++k) {
        // uniform address -> s_load_dwordx4, SGPR operands into v_fma_f32
        float4 ev = *(const float4*)(cb + (size_t)(kt + k) * D + d4 * 4);
        acc[k] = fmaf(x0, ev.x, acc[k]);
        acc[k] = fmaf(x1, ev.y, acc[k]);
        acc[k] = fmaf(x2, ev.z, acc[k]);
        acc[k] = fmaf(x3, ev.w, acc[k]);
      }
    }
#pragma unroll
    for (int k = 0; k < KW; ++k) {
      float m = ee[kt + k] - 2.0f * acc[k];  // xx term constant per t: argmin-safe
      if (m < bestv) { bestv = m; besti = kt + k; }  // strict <: first occurrence
    }
  }

  // ---- cross-wave argmin reduce (min value, tie -> smaller idx) ----
  red_val[wv * 64 + lane] = bestv;
  red_idx[wv * 64 + lane] = besti;
  __syncthreads();
  if (tid < 64) {
    float bv = red_val[tid];
    int   bi = red_idx[tid];
#pragma unroll
    for (int w = 1; w < 4; ++w) {
      float v = red_val[w * 64 + tid];
      int  ii = red_idx[w * 64 + tid];
      if (v < bv || (v == bv && ii < bi)) { bv = v; bi = ii; }
    }
    idx_sh[tid] = bi;
    out_idx[b * T_FULL + t0 + tid] = (float)bi;
    atomicAdd(&counts[bi], 1u);              // device-scope, XCD-safe
  }
  __syncthreads();

  // ---- quantized output + loss partial ----
  float lsum = 0.f;
  {
    const int t  = lane;
    const int kq = idx_sh[t];
    const float* crow = cb + (size_t)kq * D;
    float* oq = out_q + (size_t)b * D * T_FULL + t0 + t;
#pragma unroll
    for (int d0 = (tid >> 6) * 4; d0 < D; d0 += 16) {
      float4 q = *(const float4*)(crow + d0);
      float x0 = Xs[(d0 + 0) * 64 + t];
      float x1 = Xs[(d0 + 1) * 64 + t];
      float x2 = Xs[(d0 + 2) * 64 + t];
      float x3 = Xs[(d0 + 3) * 64 + t];
      float df;
      df = q.x - x0; lsum = fmaf(df, df, lsum); oq[(size_t)(d0 + 0) * T_FULL] = q.x;
      df = q.y - x1; lsum = fmaf(df, df, lsum); oq[(size_t)(d0 + 1) * T_FULL] = q.y;
      df = q.z - x2; lsum = fmaf(df, df, lsum); oq[(size_t)(d0 + 2) * T_FULL] = q.z;
      df = q.w - x3; lsum = fmaf(df, df, lsum); oq[(size_t)(d0 + 3) * T_FULL] = q.w;
    }
  }
#pragma unroll
  for (int o = 32; o > 0; o >>= 1) lsum += __shfl_down(lsum, o, 64);
  __syncthreads();                 // red_val free for reuse
  if (lane == 0) red_val[wv] = lsum;
  __syncthreads();
  if (tid == 0) lparts[blockIdx.x] = red_val[0] + red_val[1] + red_val[2] + red_val[3];
}

// ---------------- finalize: loss + perplexity ----------------
__global__ __launch_bounds__(256) void fin_kernel(const unsigned int* __restrict__ counts,
                                                  const float* __restrict__ lparts,
                                                  float* __restrict__ out) {
  int tid = threadIdx.x;
  float ent = 0.f, ls = 0.f;
#pragma unroll
  for (int i = tid; i < K; i += 256) {
    float p = (float)counts[i] * (1.0f / (float)NVEC);
    ent = fmaf(p, logf(p + 1e-10f), ent);
    ls += lparts[i];
  }
#pragma unroll
  for (int o = 32; o > 0; o >>= 1) {
    ent += __shfl_down(ent, o, 64);
    ls  += __shfl_down(ls, o, 64);
  }
  __shared__ float se[4], sl[4];
  int wv = tid >> 6, lane = tid & 63;
  if (lane == 0) { se[wv] = ent; sl[wv] = ls; }
  __syncthreads();
  if (tid == 0) {
    float e = se[0] + se[1] + se[2] + se[3];
    float l = sl[0] + sl[1] + sl[2] + sl[3];
    out[0]       = 0.25f * (l / (float)BDT);   // commitment loss
    out[1 + BDT] = expf(-e);                   // perplexity
  }
}

extern "C" void kernel_launch(void* const* d_in, const int* in_sizes, int n_in,
                              void* d_out, int out_size, void* d_ws, size_t ws_size,
                              hipStream_t stream) {
  const float* inp = (const float*)d_in[0];   // [16,128,4096] fp32
  const float* cb  = (const float*)d_in[1];   // [1024,128] fp32
  float* out = (float*)d_out;                 // [loss | q(BDT) | perp | idx(B*T)]

  unsigned int* counts = (unsigned int*)d_ws;          // 1024 u32
  float* lparts = (float*)d_ws + 1024;                 // 1024 f32
  float* ee     = (float*)d_ws + 2048;                 // 1024 f32

  hipMemsetAsync(counts, 0, K * sizeof(unsigned int), stream);
  ee_kernel<<<K, 128, 0, stream>>>(cb, ee);
  vq_main<<<1024, 256, 0, stream>>>(inp, cb, ee, counts, lparts,
                                    out + 1, out + 2 + BDT);
  fin_kernel<<<1, 256, 0, stream>>>(counts, lparts, out);
}

// Round 2
// 338.082 us; speedup vs baseline: 1.4524x; 1.4524x over previous
//
#include <hip/hip_runtime.h>

#define T_FULL 4096
#define D 128
#define K 1024
#define NVEC 65536           // 16*4096
#define BDT 8388608          // 16*128*4096
#define BT 64                // tokens per block
#define XROW 136             // padded LDS row stride in ushorts (272 B: bank-safe)

typedef unsigned short ushort_t;
typedef __bf16 bf16x8 __attribute__((ext_vector_type(8)));
typedef float f32x4 __attribute__((ext_vector_type(4)));

// truncate f32 -> bf16 bits (exact split: x - hi(x) is exact in f32)
__device__ __forceinline__ float trunc_bf(float x, ushort_t* bits) {
  union { float f; unsigned u; } a; a.f = x;
  *bits = (ushort_t)(a.u >> 16);
  union { unsigned u; float f; } b; b.u = a.u & 0xFFFF0000u;
  return b.f;
}

// ---------------- prep: ee norms + scaled (2e) 3-way bf16 split planes ----------------
__global__ __launch_bounds__(128) void prep_kernel(const float* __restrict__ cb,
    float* __restrict__ ee, ushort_t* __restrict__ Eh, ushort_t* __restrict__ Em,
    ushort_t* __restrict__ El) {
  int k = blockIdx.x, d = threadIdx.x;
  float e = cb[k * D + d];
  float v = e * e;
#pragma unroll
  for (int o = 32; o > 0; o >>= 1) v += __shfl_down(v, o, 64);
  __shared__ float tmp[2];
  if ((d & 63) == 0) tmp[d >> 6] = v;
  __syncthreads();
  if (d == 0) ee[k] = tmp[0] + tmp[1];

  float s = 2.0f * e;                       // fold the -2*dot scale (exact)
  ushort_t hb, mb, lb;
  float hf = trunc_bf(s, &hb);
  float r  = s - hf;
  float mf = trunc_bf(r, &mb);
  float r2 = r - mf;
  (void)trunc_bf(r2, &lb);
  Eh[k * D + d] = hb; Em[k * D + d] = mb; El[k * D + d] = lb;
}

// ---------------- main: MFMA distances + argmin + quantize + loss + hist ----------------
__global__ __launch_bounds__(256, 2) void vq_main(
    const float* __restrict__ inp, const float* __restrict__ cb,
    const float* __restrict__ ee,
    const ushort_t* __restrict__ Eh, const ushort_t* __restrict__ Em,
    const ushort_t* __restrict__ El,
    unsigned int* __restrict__ counts, float* __restrict__ lparts,
    float* __restrict__ out_q, float* __restrict__ out_idx) {
  __shared__ __align__(16) ushort_t Xh[BT * XROW];
  __shared__ __align__(16) ushort_t Xm[BT * XROW];
  __shared__ __align__(16) ushort_t Xl[BT * XROW];
  __shared__ float mval[2][BT];
  __shared__ int   midx[2][BT];
  __shared__ float lred[4];

  const int tid  = threadIdx.x;
  const int b    = blockIdx.x >> 6;
  const int t0   = (blockIdx.x & 63) << 6;
  const int lane = tid & 63;
  const int wv   = tid >> 6;
  const int wn   = wv >> 1;     // token half (0/1): 32 tokens
  const int wk   = wv & 1;      // code half (0/1): 64 codes of each 128-kt
  const int q    = lane >> 4;   // quad
  const int c    = lane & 15;

  // ---- stage X tile: split to 3 bf16 planes, LDS [tok][d] padded ----
  {
    const int t_loc = tid & 63;         // token
    const int dh    = tid >> 6;         // d-quarter (32 d each)
    const float* xin = inp + ((size_t)b * D + dh * 32) * T_FULL + t0 + t_loc;
    const int row = t_loc * XROW + dh * 32;
#pragma unroll
    for (int dd = 0; dd < 32; dd += 2) {
      float x0 = xin[(size_t)dd * T_FULL];
      float x1 = xin[(size_t)(dd + 1) * T_FULL];
      ushort_t h0, m0, l0, h1, m1, l1;
      float hf0 = trunc_bf(x0, &h0); float r0 = x0 - hf0;
      float mf0 = trunc_bf(r0, &m0); (void)trunc_bf(r0 - mf0, &l0);
      float hf1 = trunc_bf(x1, &h1); float r1 = x1 - hf1;
      float mf1 = trunc_bf(r1, &m1); (void)trunc_bf(r1 - mf1, &l1);
      *(unsigned*)&Xh[row + dd] = (unsigned)h0 | ((unsigned)h1 << 16);
      *(unsigned*)&Xm[row + dd] = (unsigned)m0 | ((unsigned)m1 << 16);
      *(unsigned*)&Xl[row + dd] = (unsigned)l0 | ((unsigned)l1 << 16);
    }
  }
  __syncthreads();

  // per-lane running argmin for token slots [nsub][reg] (tokens wn*32+nsub*16+q*4+reg)
  float bv[2][4];
  int   bi[2][4];
#pragma unroll
  for (int n = 0; n < 2; ++n)
#pragma unroll
    for (int r = 0; r < 4; ++r) { bv[n][r] = 3.4e38f; bi[n][r] = 0; }

  for (int kt = 0; kt < K; kt += 128) {
    const int cbase = kt + wk * 64;
    f32x4 acc[2][4];
#pragma unroll
    for (int n = 0; n < 2; ++n)
#pragma unroll
      for (int k = 0; k < 4; ++k) acc[n][k] = (f32x4){0.f, 0.f, 0.f, 0.f};

    float eev[4];
#pragma unroll
    for (int k = 0; k < 4; ++k) eev[k] = ee[cbase + k * 16 + c];

#pragma unroll
    for (int dc = 0; dc < 4; ++dc) {
      bf16x8 Bh[4], Bm[4], Bl[4];
#pragma unroll
      for (int k = 0; k < 4; ++k) {
        const size_t eo = (size_t)(cbase + k * 16 + c) * D + dc * 32 + q * 8;
        Bh[k] = *(const bf16x8*)(Eh + eo);
        Bm[k] = *(const bf16x8*)(Em + eo);
        Bl[k] = *(const bf16x8*)(El + eo);
      }
#pragma unroll
      for (int n = 0; n < 2; ++n) {
        const int xo = (wn * 32 + n * 16 + c) * XROW + dc * 32 + q * 8;
        bf16x8 Ah = *(const bf16x8*)(Xh + xo);
        bf16x8 Am = *(const bf16x8*)(Xm + xo);
        bf16x8 Al = *(const bf16x8*)(Xl + xo);
#pragma unroll
        for (int k = 0; k < 4; ++k) {
          f32x4 a = acc[n][k];
          a = __builtin_amdgcn_mfma_f32_16x16x32_bf16(Ah, Bh[k], a, 0, 0, 0);
          a = __builtin_amdgcn_mfma_f32_16x16x32_bf16(Ah, Bm[k], a, 0, 0, 0);
          a = __builtin_amdgcn_mfma_f32_16x16x32_bf16(Am, Bh[k], a, 0, 0, 0);
          a = __builtin_amdgcn_mfma_f32_16x16x32_bf16(Ah, Bl[k], a, 0, 0, 0);
          a = __builtin_amdgcn_mfma_f32_16x16x32_bf16(Al, Bh[k], a, 0, 0, 0);
          a = __builtin_amdgcn_mfma_f32_16x16x32_bf16(Am, Bm[k], a, 0, 0, 0);
          acc[n][k] = a;
        }
      }
    }

    // dist = ee - 2*dot; codes ascending over (kt, k) -> strict < keeps first occurrence
#pragma unroll
    for (int n = 0; n < 2; ++n)
#pragma unroll
      for (int k = 0; k < 4; ++k) {
        const int code = cbase + k * 16 + c;
#pragma unroll
        for (int r = 0; r < 4; ++r) {
          float dist = eev[k] - acc[n][k][r];
          if (dist < bv[n][r]) { bv[n][r] = dist; bi[n][r] = code; }
        }
      }
  }

  // cross-lane argmin over the 16 cols (lanes within each quad group)
#pragma unroll
  for (int m = 1; m <= 8; m <<= 1) {
#pragma unroll
    for (int n = 0; n < 2; ++n)
#pragma unroll
      for (int r = 0; r < 4; ++r) {
        float ov = __shfl_xor(bv[n][r], m, 64);
        int   oi = __shfl_xor(bi[n][r], m, 64);
        if (ov < bv[n][r] || (ov == bv[n][r] && oi < bi[n][r])) {
          bv[n][r] = ov; bi[n][r] = oi;
        }
      }
  }
  if (c == 0) {
#pragma unroll
    for (int n = 0; n < 2; ++n)
#pragma unroll
      for (int r = 0; r < 4; ++r) {
        const int t_loc = wn * 32 + n * 16 + q * 4 + r;
        mval[wk][t_loc] = bv[n][r];
        midx[wk][t_loc] = bi[n][r];
      }
  }
  __syncthreads();

  // merge the two code halves, emit idx + histogram
  if (tid < BT) {
    float v0 = mval[0][tid], v1 = mval[1][tid];
    int   i0 = midx[0][tid], i1 = midx[1][tid];
    int ki = (v1 < v0 || (v1 == v0 && i1 < i0)) ? i1 : i0;
    midx[0][tid] = ki;
    out_idx[b * T_FULL + t0 + tid] = (float)ki;
    atomicAdd(&counts[ki], 1u);
  }
  __syncthreads();

  // quantized output + loss partial (re-read x from global; coalesced in t)
  float lsum = 0.f;
  {
    const int t_loc = tid & 63;
    const int dh    = tid >> 6;
    const int kq    = midx[0][t_loc];
    const float* crow = cb + (size_t)kq * D + dh * 32;
    const float* xrow = inp + ((size_t)b * D + dh * 32) * T_FULL + t0 + t_loc;
    float* qrow = out_q + ((size_t)b * D + dh * 32) * T_FULL + t0 + t_loc;
#pragma unroll
    for (int dd = 0; dd < 32; ++dd) {
      float qv = crow[dd];
      float xv = xrow[(size_t)dd * T_FULL];
      float df = qv - xv;
      lsum = fmaf(df, df, lsum);
      qrow[(size_t)dd * T_FULL] = qv;
    }
  }
#pragma unroll
  for (int o = 32; o > 0; o >>= 1) lsum += __shfl_down(lsum, o, 64);
  if (lane == 0) lred[wv] = lsum;
  __syncthreads();
  if (tid == 0) lparts[blockIdx.x] = lred[0] + lred[1] + lred[2] + lred[3];
}

// ---------------- finalize: loss + perplexity ----------------
__global__ __launch_bounds__(256) void fin_kernel(const unsigned int* __restrict__ counts,
                                                  const float* __restrict__ lparts,
                                                  float* __restrict__ out) {
  int tid = threadIdx.x;
  float ent = 0.f, ls = 0.f;
#pragma unroll
  for (int i = tid; i < K; i += 256) {
    float p = (float)counts[i] * (1.0f / (float)NVEC);
    ent = fmaf(p, logf(p + 1e-10f), ent);
    ls += lparts[i];
  }
#pragma unroll
  for (int o = 32; o > 0; o >>= 1) {
    ent += __shfl_down(ent, o, 64);
    ls  += __shfl_down(ls, o, 64);
  }
  __shared__ float se[4], sl[4];
  int wv = tid >> 6, lane = tid & 63;
  if (lane == 0) { se[wv] = ent; sl[wv] = ls; }
  __syncthreads();
  if (tid == 0) {
    float e = se[0] + se[1] + se[2] + se[3];
    float l = sl[0] + sl[1] + sl[2] + sl[3];
    out[0]       = 0.25f * (l / (float)BDT);
    out[1 + BDT] = expf(-e);
  }
}

extern "C" void kernel_launch(void* const* d_in, const int* in_sizes, int n_in,
                              void* d_out, int out_size, void* d_ws, size_t ws_size,
                              hipStream_t stream) {
  const float* inp = (const float*)d_in[0];   // [16,128,4096] fp32
  const float* cb  = (const float*)d_in[1];   // [1024,128] fp32
  float* out = (float*)d_out;                 // [loss | q(BDT) | perp | idx(B*T)]

  char* ws = (char*)d_ws;
  unsigned int* counts = (unsigned int*)ws;                 // 4 KB
  float*    lparts = (float*)(ws + 4096);                   // 4 KB (1024 blocks)
  float*    ee     = (float*)(ws + 8192);                   // 4 KB
  ushort_t* Eh     = (ushort_t*)(ws + 12288);               // 256 KB
  ushort_t* Em     = (ushort_t*)(ws + 12288 + 262144);      // 256 KB
  ushort_t* El     = (ushort_t*)(ws + 12288 + 524288);      // 256 KB

  hipMemsetAsync(counts, 0, K * sizeof(unsigned int), stream);
  prep_kernel<<<K, 128, 0, stream>>>(cb, ee, Eh, Em, El);
  vq_main<<<NVEC / BT, 256, 0, stream>>>(inp, cb, ee, Eh, Em, El,
                                         counts, lparts, out + 1, out + 2 + BDT);
  fin_kernel<<<1, 256, 0, stream>>>(counts, lparts, out);
}

// Round 3
// 196.313 us; speedup vs baseline: 2.5013x; 1.7222x over previous
//
#include <hip/hip_runtime.h>

#define T_FULL 4096
#define D 128
#define K 1024
#define NVEC 65536           // 16*4096
#define BDT 8388608          // 16*128*4096
#define BT 128               // tokens per block
#define NBLK (NVEC / BT)     // 512 blocks
#define KT 32                // codes per staged tile
#define NIT (K / KT)         // 32 iterations
#define PLANE_B (K * D * 2)  // 262144 bytes per bf16 plane
#define TILE_B (3 * KT * D * 2)   // 24576 bytes per staged tile (3 planes)

typedef unsigned short ushort_t;
typedef __bf16 bf16x8 __attribute__((ext_vector_type(8)));
typedef float f32x4 __attribute__((ext_vector_type(4)));

// truncate f32 -> bf16 bits (exact split: x - hi(x) is exact in f32)
__device__ __forceinline__ float trunc_bf(float x, ushort_t* bits) {
  union { float f; unsigned u; } a; a.f = x;
  *bits = (ushort_t)(a.u >> 16);
  union { unsigned u; float f; } b; b.u = a.u & 0xFFFF0000u;
  return b.f;
}
__device__ __forceinline__ __bf16 bf_bits(ushort_t u) {
  union { ushort_t u; __bf16 h; } c; c.u = u; return c.h;
}

#define MFMA(a, b, c) __builtin_amdgcn_mfma_f32_16x16x32_bf16((a), (b), (c), 0, 0, 0)

#define GLOAD_LDS(g, l)                                                        \
  __builtin_amdgcn_global_load_lds(                                            \
      (const __attribute__((address_space(1))) unsigned int*)(g),              \
      (__attribute__((address_space(3))) unsigned int*)(l), 16, 0, 0)

// ---------------- prep: ee norms + scaled (2e) 3-way bf16 split planes ----------------
__global__ __launch_bounds__(128) void prep_kernel(const float* __restrict__ cb,
    float* __restrict__ ee, ushort_t* __restrict__ Eh, ushort_t* __restrict__ Em,
    ushort_t* __restrict__ El) {
  int k = blockIdx.x, d = threadIdx.x;
  float e = cb[k * D + d];
  float v = e * e;
#pragma unroll
  for (int o = 32; o > 0; o >>= 1) v += __shfl_down(v, o, 64);
  __shared__ float tmp[2];
  if ((d & 63) == 0) tmp[d >> 6] = v;
  __syncthreads();
  if (d == 0) ee[k] = tmp[0] + tmp[1];

  float s = 2.0f * e;                       // fold the -2*dot scale (exact)
  ushort_t hb, mb, lb;
  float hf = trunc_bf(s, &hb);
  float r  = s - hf;
  float mf = trunc_bf(r, &mb);
  (void)trunc_bf(r - mf, &lb);
  Eh[k * D + d] = hb; Em[k * D + d] = mb; El[k * D + d] = lb;
}

// ---------------- main: A-in-regs, B dbuf in LDS via global_load_lds ----------------
__global__ __launch_bounds__(256, 2) void vq_main(
    const float* __restrict__ inp, const float* __restrict__ cb,
    const float* __restrict__ ee, const ushort_t* __restrict__ Eplanes,
    unsigned int* __restrict__ counts, float* __restrict__ lparts,
    float* __restrict__ out_q, float* __restrict__ out_idx) {
  __shared__ __align__(16) ushort_t Bs[2 * 3 * KT * D];   // 48 KB, XOR-swizzled
  __shared__ float ee_sh[K];                              // 4 KB
  __shared__ int   midx[BT];
  __shared__ float lred[4];

  const int tid  = threadIdx.x;
  const int lane = tid & 63;
  const int w    = tid >> 6;        // wave: owns tokens w*32..w*32+31
  const int c    = lane & 15;       // MFMA col (code) / A row (token)
  const int q    = lane >> 4;       // quad
  const int b    = blockIdx.x >> 5;
  const int t0   = (blockIdx.x & 31) * BT;

  // --- per-lane staging offsets (16B-swizzled: lds slot s -> global dg = (s&15)^(code&15)) ---
  unsigned soff[6], sldsoff[6];
#pragma unroll
  for (int i = 0; i < 6; ++i) {
    int flatb = w * 384 + i * 64;          // wave-uniform slot base (0..1472)
    int p     = flatb >> 9;                // plane 0..2 (uniform per instr)
    int s     = (flatb & 511) + lane;      // slot within plane (code*16 + dg')
    int code  = s >> 4;
    int dg    = (s & 15) ^ (code & 15);
    soff[i]    = (unsigned)(p * PLANE_B + code * 256 + dg * 16);
    sldsoff[i] = (unsigned)(flatb * 16);   // lds byte offset (uniform)
  }
  const char* Eb = (const char*)Eplanes;

  // --- issue stage of buffer 0 (kt = 0) ---
#pragma unroll
  for (int i = 0; i < 6; ++i)
    GLOAD_LDS(Eb + soff[i], (char*)Bs + sldsoff[i]);

  // --- X -> registers, exact 3-way bf16 split (A-fragment layout) ---
  bf16x8 Ah[2][4], Am[2][4], Al[2][4];
  {
    const float* xin = inp + (size_t)b * D * T_FULL + t0 + w * 32 + c;
#pragma unroll
    for (int n = 0; n < 2; ++n)
#pragma unroll
      for (int dc = 0; dc < 4; ++dc) {
        bf16x8 ah, am, al;
#pragma unroll
        for (int j = 0; j < 8; ++j) {
          int d = dc * 32 + q * 8 + j;
          float x = xin[(size_t)d * T_FULL + n * 16];
          ushort_t hb, mb, lb;
          float hf = trunc_bf(x, &hb);
          float r  = x - hf;
          float mf = trunc_bf(r, &mb);
          (void)trunc_bf(r - mf, &lb);
          ah[j] = bf_bits(hb); am[j] = bf_bits(mb); al[j] = bf_bits(lb);
        }
        Ah[n][dc] = ah; Am[n][dc] = am; Al[n][dc] = al;
      }
  }
  // --- ee -> LDS ---
#pragma unroll
  for (int i = tid; i < K; i += 256) ee_sh[i] = ee[i];
  __syncthreads();

  float bv[2][4];
  int   bi[2][4];
#pragma unroll
  for (int n = 0; n < 2; ++n)
#pragma unroll
    for (int r = 0; r < 4; ++r) { bv[n][r] = 3.4e38f; bi[n][r] = 0; }

  for (int it = 0; it < NIT; ++it) {
    const int kt = it * KT;
    const int bb = it & 1;

    // prefetch next tile into buffer bb^1 (wraps harmlessly on last iter)
    {
      const int ktn = (kt + KT) & (K - 1);
      const unsigned lb = (unsigned)((bb ^ 1) * TILE_B);
#pragma unroll
      for (int i = 0; i < 6; ++i)
        GLOAD_LDS(Eb + (size_t)ktn * 256 + soff[i], (char*)Bs + lb + sldsoff[i]);
    }

    // compute on buffer bb
    f32x4 acc[2][2];
#pragma unroll
    for (int n = 0; n < 2; ++n)
#pragma unroll
      for (int kf = 0; kf < 2; ++kf) acc[n][kf] = (f32x4){0.f, 0.f, 0.f, 0.f};

    const char* Bp = (const char*)Bs + bb * TILE_B;
#pragma unroll
    for (int dc = 0; dc < 4; ++dc) {
      const int sw = ((dc * 4 + q) ^ c) * 16;       // de-swizzle
      bf16x8 Bh[2], Bm[2], Bl[2];
#pragma unroll
      for (int kf = 0; kf < 2; ++kf) {
        const int ro = (kf * 16 + c) * 256 + sw;
        Bh[kf] = *(const bf16x8*)(Bp + ro);
        Bm[kf] = *(const bf16x8*)(Bp + 8192 + ro);
        Bl[kf] = *(const bf16x8*)(Bp + 16384 + ro);
      }
#pragma unroll
      for (int n = 0; n < 2; ++n)
#pragma unroll
        for (int kf = 0; kf < 2; ++kf) {
          f32x4 a = acc[n][kf];
          a = MFMA(Ah[n][dc], Bh[kf], a);
          a = MFMA(Ah[n][dc], Bm[kf], a);
          a = MFMA(Am[n][dc], Bh[kf], a);
          a = MFMA(Ah[n][dc], Bl[kf], a);
          a = MFMA(Al[n][dc], Bh[kf], a);
          a = MFMA(Am[n][dc], Bm[kf], a);
          acc[n][kf] = a;
        }
    }

    // argmin update: dist = ee - 2*x.e ; codes ascending -> strict < = first occurrence
#pragma unroll
    for (int kf = 0; kf < 2; ++kf) {
      const int code = kt + kf * 16 + c;
      const float eev = ee_sh[code];
#pragma unroll
      for (int n = 0; n < 2; ++n)
#pragma unroll
        for (int r = 0; r < 4; ++r) {
          float dist = eev - acc[n][kf][r];
          if (dist < bv[n][r]) { bv[n][r] = dist; bi[n][r] = code; }
        }
    }
    __syncthreads();
  }

  // --- cross-lane argmin over the 16 code-cols (tie -> smaller idx) ---
#pragma unroll
  for (int m = 1; m <= 8; m <<= 1)
#pragma unroll
    for (int n = 0; n < 2; ++n)
#pragma unroll
      for (int r = 0; r < 4; ++r) {
        float ov = __shfl_xor(bv[n][r], m, 64);
        int   oi = __shfl_xor(bi[n][r], m, 64);
        if (ov < bv[n][r] || (ov == bv[n][r] && oi < bi[n][r])) {
          bv[n][r] = ov; bi[n][r] = oi;
        }
      }
  if (c == 0) {
#pragma unroll
    for (int n = 0; n < 2; ++n)
#pragma unroll
      for (int r = 0; r < 4; ++r)
        midx[w * 32 + n * 16 + q * 4 + r] = bi[n][r];
  }
  __syncthreads();

  if (tid < BT) {
    int ki = midx[tid];
    out_idx[(size_t)b * T_FULL + t0 + tid] = (float)ki;
    atomicAdd(&counts[ki], 1u);
  }

  // --- quantized output + loss partial ---
  float lsum = 0.f;
  {
    const int t  = tid & 127;
    const int dh = tid >> 7;            // d-half: 0..63 / 64..127
    const int kq = midx[t];
    const float* crow = cb + (size_t)kq * D + dh * 64;
    const float* xrow = inp + ((size_t)b * D + dh * 64) * T_FULL + t0 + t;
    float*       qrow = out_q + ((size_t)b * D + dh * 64) * T_FULL + t0 + t;
#pragma unroll
    for (int dd = 0; dd < 64; dd += 4) {
      float4 qv = *(const float4*)(crow + dd);
      float x0 = xrow[(size_t)(dd + 0) * T_FULL];
      float x1 = xrow[(size_t)(dd + 1) * T_FULL];
      float x2 = xrow[(size_t)(dd + 2) * T_FULL];
      float x3 = xrow[(size_t)(dd + 3) * T_FULL];
      float df;
      df = qv.x - x0; lsum = fmaf(df, df, lsum); qrow[(size_t)(dd + 0) * T_FULL] = qv.x;
      df = qv.y - x1; lsum = fmaf(df, df, lsum); qrow[(size_t)(dd + 1) * T_FULL] = qv.y;
      df = qv.z - x2; lsum = fmaf(df, df, lsum); qrow[(size_t)(dd + 2) * T_FULL] = qv.z;
      df = qv.w - x3; lsum = fmaf(df, df, lsum); qrow[(size_t)(dd + 3) * T_FULL] = qv.w;
    }
  }
#pragma unroll
  for (int o = 32; o > 0; o >>= 1) lsum += __shfl_down(lsum, o, 64);
  if (lane == 0) lred[w] = lsum;
  __syncthreads();
  if (tid == 0) lparts[blockIdx.x] = lred[0] + lred[1] + lred[2] + lred[3];
}

// ---------------- finalize: loss + perplexity ----------------
__global__ __launch_bounds__(256) void fin_kernel(const unsigned int* __restrict__ counts,
                                                  const float* __restrict__ lparts,
                                                  float* __restrict__ out) {
  int tid = threadIdx.x;
  float ent = 0.f, ls = 0.f;
#pragma unroll
  for (int i = tid; i < K; i += 256) {
    float p = (float)counts[i] * (1.0f / (float)NVEC);
    ent = fmaf(p, logf(p + 1e-10f), ent);
  }
#pragma unroll
  for (int i = tid; i < NBLK; i += 256) ls += lparts[i];
#pragma unroll
  for (int o = 32; o > 0; o >>= 1) {
    ent += __shfl_down(ent, o, 64);
    ls  += __shfl_down(ls, o, 64);
  }
  __shared__ float se[4], sl[4];
  int wv = tid >> 6, lane = tid & 63;
  if (lane == 0) { se[wv] = ent; sl[wv] = ls; }
  __syncthreads();
  if (tid == 0) {
    float e = se[0] + se[1] + se[2] + se[3];
    float l = sl[0] + sl[1] + sl[2] + sl[3];
    out[0]       = 0.25f * (l / (float)BDT);
    out[1 + BDT] = expf(-e);
  }
}

extern "C" void kernel_launch(void* const* d_in, const int* in_sizes, int n_in,
                              void* d_out, int out_size, void* d_ws, size_t ws_size,
                              hipStream_t stream) {
  const float* inp = (const float*)d_in[0];   // [16,128,4096] fp32
  const float* cb  = (const float*)d_in[1];   // [1024,128] fp32
  float* out = (float*)d_out;                 // [loss | q(BDT) | perp | idx(B*T)]

  char* ws = (char*)d_ws;
  unsigned int* counts = (unsigned int*)ws;                 // 4 KB
  float*    lparts = (float*)(ws + 4096);                   // 4 KB
  float*    ee     = (float*)(ws + 8192);                   // 4 KB
  ushort_t* Eh     = (ushort_t*)(ws + 12288);               // 256 KB  (Eh|Em|El contiguous)
  ushort_t* Em     = (ushort_t*)(ws + 12288 + PLANE_B);     // 256 KB
  ushort_t* El     = (ushort_t*)(ws + 12288 + 2 * PLANE_B); // 256 KB

  hipMemsetAsync(counts, 0, K * sizeof(unsigned int), stream);
  prep_kernel<<<K, 128, 0, stream>>>(cb, ee, Eh, Em, El);
  vq_main<<<NBLK, 256, 0, stream>>>(inp, cb, ee, Eh, counts, lparts,
                                    out + 1, out + 2 + BDT);
  fin_kernel<<<1, 256, 0, stream>>>(counts, lparts, out);
}